// Round 2
// baseline (612.452 us; speedup 1.0000x reference)
//
#include <hip/hip_runtime.h>
#include <cstdint>
#include <cstddef>

typedef __attribute__((ext_vector_type(4))) float f32x4;
typedef __attribute__((ext_vector_type(8))) short bf16x8;

#define S_LEN 2048
#define HDIM 4096
#define QKVD 6144
#define NHEAD 32
#define NKVH 8
#define HD 128
#define ATT_SCALE 0.08838834764831845f

// fp32 -> bf16 RNE (finite inputs only)
__device__ __forceinline__ short f2bf(float f) {
  unsigned int u = __float_as_uint(f);
  u += 0x7FFFu + ((u >> 16) & 1u);
  return (short)(u >> 16);
}

// async global->LDS, 16B per lane. LDS dest = wave-uniform base + lane*16.
__device__ __forceinline__ void gl_lds16(const short* g, short* l) {
  __builtin_amdgcn_global_load_lds((const __attribute__((address_space(1))) void*)g,
                                   (__attribute__((address_space(3))) void*)l,
                                   16, 0, 0);
}

__global__ void cvt_kernel(const float* __restrict__ in, short* __restrict__ out, int n) {
  int i = (blockIdx.x * blockDim.x + threadIdx.x) * 4;
  if (i >= n) return;
  const float4 v = *reinterpret_cast<const float4*>(in + i);
  short4 o;
  o.x = f2bf(v.x); o.y = f2bf(v.y); o.z = f2bf(v.z); o.w = f2bf(v.w);
  *reinterpret_cast<short4*>(out + i) = o;
}

// C[M][N] = A[M][K] * B[N][K]^T (bf16 in, fp32 out), 128x128 tile, BK=32,
// m97 structure: global_load_lds width=16, 2 barriers per K-step.
__global__ __launch_bounds__(256) void gemm_lds(const short* __restrict__ A,
                                                const short* __restrict__ B,
                                                float* __restrict__ C,
                                                int M, int N, int K) {
  __shared__ short lA[128 * 32];
  __shared__ short lB[128 * 32];
  const int t = threadIdx.x;
  const int w = t >> 6, lane = t & 63;
  const int l15 = lane & 15, l4 = lane >> 4;
  const int tm = blockIdx.y * 128, tn = blockIdx.x * 128;
  const int wr = (w >> 1) * 64, wc = (w & 1) * 64;

  // staging: 512 chunks of 16B per tile; wave w covers chunks [w*128, w*128+128)
  const int c0 = w * 128 + lane, c1 = c0 + 64;
  const short* gA0 = A + (size_t)(tm + (c0 >> 2)) * K + (c0 & 3) * 8;
  const short* gA1 = A + (size_t)(tm + (c1 >> 2)) * K + (c1 & 3) * 8;
  const short* gB0 = B + (size_t)(tn + (c0 >> 2)) * K + (c0 & 3) * 8;
  const short* gB1 = B + (size_t)(tn + (c1 >> 2)) * K + (c1 & 3) * 8;
  short* lA0 = lA + c0 * 8; short* lA1 = lA + c1 * 8;
  short* lB0 = lB + c0 * 8; short* lB1 = lB + c1 * 8;

  f32x4 acc[4][4] = {};

  for (int k0 = 0; k0 < K; k0 += 32) {
    gl_lds16(gA0 + k0, lA0);
    gl_lds16(gA1 + k0, lA1);
    gl_lds16(gB0 + k0, lB0);
    gl_lds16(gB1 + k0, lB1);
    __syncthreads();  // compiler emits vmcnt(0) drain before s_barrier
    bf16x8 af[4], bfr[4];
#pragma unroll
    for (int m = 0; m < 4; ++m)
      af[m] = *reinterpret_cast<const bf16x8*>(lA + (wr + m * 16 + l15) * 32 + l4 * 8);
#pragma unroll
    for (int n = 0; n < 4; ++n)
      bfr[n] = *reinterpret_cast<const bf16x8*>(lB + (wc + n * 16 + l15) * 32 + l4 * 8);
#pragma unroll
    for (int m = 0; m < 4; ++m)
#pragma unroll
      for (int n = 0; n < 4; ++n)
        acc[m][n] = __builtin_amdgcn_mfma_f32_16x16x32_bf16(af[m], bfr[n], acc[m][n], 0, 0, 0);
    __syncthreads();
  }
#pragma unroll
  for (int m = 0; m < 4; ++m)
#pragma unroll
    for (int n = 0; n < 4; ++n)
#pragma unroll
      for (int r = 0; r < 4; ++r) {
        int rr = tm + wr + m * 16 + l4 * 4 + r;
        int cc = tn + wc + n * 16 + l15;
        C[(size_t)rr * N + cc] = acc[m][n][r];
      }
}

// qkv fp32 [S][6144] -> roped bf16 Q[NH][S][HD], K[NKV][S][HD], Vt[NKV][HD][S]
__global__ void rope_kernel(const float* __restrict__ qkv,
                            const float* __restrict__ cb,
                            const float* __restrict__ sb,
                            short* __restrict__ Q,
                            short* __restrict__ Kx,
                            short* __restrict__ Vt) {
  int tid = blockIdx.x * blockDim.x + threadIdx.x;
  int s = tid / QKVD;
  int j = tid - s * QKVD;
  int g = j / 768;
  int idx = j - g * 768;
  float val = qkv[tid];
  if (idx < 640) {
    int part = idx >> 7;  // 0..3 = q heads in group, 4 = k
    int d = idx & 127;
    int d2 = (d < 64) ? d + 64 : d - 64;
    float pv = qkv[(size_t)s * QKVD + g * 768 + part * 128 + d2];
    float c = cb[s * HD + d], sn = sb[s * HD + d];
    float ov = (d < 64) ? (val * c - pv * sn) : (val * c + pv * sn);
    if (part < 4) {
      int hh = g * 4 + part;
      Q[((size_t)hh * S_LEN + s) * HD + d] = f2bf(ov);
    } else {
      Kx[((size_t)g * S_LEN + s) * HD + d] = f2bf(ov);
    }
  } else {
    int d = idx - 640;
    Vt[((size_t)(g * HD + d)) * S_LEN + s] = f2bf(val);  // transposed V
  }
}

// flash attention v2: 4 waves/block = 4 q-heads of one KV group (shared K/V),
// each wave owns a 16-row q-tile; KV tile = 64; V pre-transposed in global;
// no __syncthreads; per-lane deferred sum.
__global__ __launch_bounds__(256) void attn_kernel(const short* __restrict__ Q,
                                                   const short* __restrict__ Kx,
                                                   const short* __restrict__ Vt,
                                                   short* __restrict__ AO) {
  __shared__ short lP[4 * 16 * 72];  // per-wave P[16][64], row stride 72 (conflict-break)
  const int w = threadIdx.x >> 6, lane = threadIdx.x & 63;
  const int l15 = lane & 15, l4 = lane >> 4;
  const int kvh = blockIdx.x, qt = blockIdx.y;
  const int h = kvh * 4 + w;
  short* P = lP + w * (16 * 72);

  bf16x8 qf[4];
  const short* qrow = Q + ((size_t)h * S_LEN + qt * 16 + l15) * HD + l4 * 8;
#pragma unroll
  for (int fd = 0; fd < 4; ++fd)
    qf[fd] = *reinterpret_cast<const bf16x8*>(qrow + fd * 32);

  f32x4 o[8] = {};
  float m_run[4] = {-1e30f, -1e30f, -1e30f, -1e30f};
  float lsum[4] = {0.f, 0.f, 0.f, 0.f};  // per-lane partial; reduced at end

  const short* Kb = Kx + (size_t)kvh * S_LEN * HD;
  const short* Vb = Vt + (size_t)kvh * HD * S_LEN;  // [HD][S]
  const int nkt = (qt * 16) / 64 + 1;

  for (int kt = 0; kt < nkt; ++kt) {
    const int c0 = kt * 64;
    // QK^T: S[16q][64kv]
    f32x4 sf[4] = {};
#pragma unroll
    for (int n = 0; n < 4; ++n) {
      const short* krow = Kb + (size_t)(c0 + n * 16 + l15) * HD + l4 * 8;
#pragma unroll
      for (int fd = 0; fd < 4; ++fd) {
        bf16x8 kf = *reinterpret_cast<const bf16x8*>(krow + fd * 32);
        sf[n] = __builtin_amdgcn_mfma_f32_16x16x32_bf16(qf[fd], kf, sf[n], 0, 0, 0);
      }
    }
    const bool lastt = (kt == nkt - 1);
#pragma unroll
    for (int n = 0; n < 4; ++n)
#pragma unroll
      for (int r = 0; r < 4; ++r) {
        float v = sf[n][r] * ATT_SCALE;
        if (lastt && (c0 + n * 16 + l15) > (qt * 16 + l4 * 4 + r)) v = -1e30f;
        sf[n][r] = v;
      }
    float alpha[4];
#pragma unroll
    for (int r = 0; r < 4; ++r) {
      float mx = fmaxf(fmaxf(sf[0][r], sf[1][r]), fmaxf(sf[2][r], sf[3][r]));
      mx = fmaxf(mx, __shfl_xor(mx, 1, 64));
      mx = fmaxf(mx, __shfl_xor(mx, 2, 64));
      mx = fmaxf(mx, __shfl_xor(mx, 4, 64));
      mx = fmaxf(mx, __shfl_xor(mx, 8, 64));
      float mnew = fmaxf(m_run[r], mx);
      alpha[r] = __expf(m_run[r] - mnew);
      m_run[r] = mnew;
      float ps = 0.f;
#pragma unroll
      for (int n = 0; n < 4; ++n) {
        float e = __expf(sf[n][r] - mnew);
        sf[n][r] = e;
        ps += e;
      }
      lsum[r] = lsum[r] * alpha[r] + ps;
    }
#pragma unroll
    for (int fd = 0; fd < 8; ++fd) {
      o[fd][0] *= alpha[0]; o[fd][1] *= alpha[1];
      o[fd][2] *= alpha[2]; o[fd][3] *= alpha[3];
    }
    // P -> LDS (A-fragment transpose), per-wave buffer, no cross-wave sync
#pragma unroll
    for (int n = 0; n < 4; ++n)
#pragma unroll
      for (int r = 0; r < 4; ++r)
        P[(l4 * 4 + r) * 72 + n * 16 + l15] = f2bf(sf[n][r]);
    asm volatile("s_waitcnt lgkmcnt(0)" ::: "memory");
    __builtin_amdgcn_sched_barrier(0);
    bf16x8 pf0 = *reinterpret_cast<const bf16x8*>(P + l15 * 72 + l4 * 8);
    bf16x8 pf1 = *reinterpret_cast<const bf16x8*>(P + l15 * 72 + 32 + l4 * 8);
    // PV: O[16q][128d] += P[16q][64kv] * V[64kv][128d] (V^T direct from global)
#pragma unroll
    for (int fd = 0; fd < 8; ++fd) {
      const short* vrow = Vb + (size_t)(fd * 16 + l15) * S_LEN + c0 + l4 * 8;
      bf16x8 vf0 = *reinterpret_cast<const bf16x8*>(vrow);
      bf16x8 vf1 = *reinterpret_cast<const bf16x8*>(vrow + 32);
      o[fd] = __builtin_amdgcn_mfma_f32_16x16x32_bf16(pf0, vf0, o[fd], 0, 0, 0);
      o[fd] = __builtin_amdgcn_mfma_f32_16x16x32_bf16(pf1, vf1, o[fd], 0, 0, 0);
    }
  }
  float inv[4];
#pragma unroll
  for (int r = 0; r < 4; ++r) {
    float s = lsum[r];
    s += __shfl_xor(s, 1, 64);
    s += __shfl_xor(s, 2, 64);
    s += __shfl_xor(s, 4, 64);
    s += __shfl_xor(s, 8, 64);
    inv[r] = 1.f / s;
  }
#pragma unroll
  for (int fd = 0; fd < 8; ++fd)
#pragma unroll
    for (int r = 0; r < 4; ++r)
      AO[(size_t)(qt * 16 + l4 * 4 + r) * HDIM + h * HD + fd * 16 + l15] =
          f2bf(o[fd][r] * inv[r]);
}

extern "C" void kernel_launch(void* const* d_in, const int* in_sizes, int n_in,
                              void* d_out, int out_size, void* d_ws, size_t ws_size,
                              hipStream_t stream) {
  const float* hidden = (const float*)d_in[0];
  const float* w_attn = (const float*)d_in[1];
  const float* w_proj = (const float*)d_in[2];
  const float* rcos = (const float*)d_in[3];
  const float* rsin = (const float*)d_in[4];
  float* out = (float*)d_out;
  char* ws = (char*)d_ws;

  // workspace layout (112 MiB total, overlaid):
  //  [0,16Mi)    Xb (bf16 X)          -> reused as AO after gemm1
  //  [16,64Mi)   Wab (bf16 w_attn)    -> reused as Qb[16,32) Kb[32,36) Vt[36,40) after gemm1
  //  [64,112Mi)  QKVf (fp32 qkv)      -> reused as Wpb (bf16 w_proj) after rope
  short* Xb  = (short*)(ws);
  short* Wab = (short*)(ws + (16u << 20));
  short* Qb  = (short*)(ws + (16u << 20));
  short* Kb  = (short*)(ws + (32u << 20));
  short* Vtb = (short*)(ws + (36u << 20));
  float* QKVf = (float*)(ws + (64u << 20));
  short* Wpb = (short*)(ws + (64u << 20));
  short* AO  = Xb;

  const int nX = S_LEN * HDIM;       // 8388608
  const int nWa = QKVD * HDIM;       // 25165824
  const int nWp = HDIM * HDIM;       // 16777216

  cvt_kernel<<<nX / 1024, 256, 0, stream>>>(hidden, Xb, nX);
  cvt_kernel<<<nWa / 1024, 256, 0, stream>>>(w_attn, Wab, nWa);
  gemm_lds<<<dim3(QKVD / 128, S_LEN / 128), 256, 0, stream>>>(Xb, Wab, QKVf, S_LEN, QKVD, HDIM);
  rope_kernel<<<(S_LEN * QKVD) / 256, 256, 0, stream>>>(QKVf, rcos, rsin, Qb, Kb, Vtb);
  cvt_kernel<<<nWp / 1024, 256, 0, stream>>>(w_proj, Wpb, nWp);
  attn_kernel<<<dim3(NKVH, S_LEN / 16), 256, 0, stream>>>(Qb, Kb, Vtb, AO);
  gemm_lds<<<dim3(HDIM / 128, S_LEN / 128), 256, 0, stream>>>(AO, Wpb, out, S_LEN, HDIM, HDIM);
}

// Round 3
// 523.298 us; speedup vs baseline: 1.1704x; 1.1704x over previous
//
#include <hip/hip_runtime.h>
#include <cstdint>
#include <cstddef>

typedef __attribute__((ext_vector_type(4))) float f32x4;
typedef __attribute__((ext_vector_type(8))) short bf16x8;

#define S_LEN 2048
#define HDIM 4096
#define QKVD 6144
#define NHEAD 32
#define NKVH 8
#define HD 128
#define ATT_SCALE 0.08838834764831845f

// fp32 -> bf16 RNE (finite inputs only)
__device__ __forceinline__ short f2bf(float f) {
  unsigned int u = __float_as_uint(f);
  u += 0x7FFFu + ((u >> 16) & 1u);
  return (short)(u >> 16);
}

// async global->LDS, 16B per lane. LDS dest = wave-uniform base + lane*16.
__device__ __forceinline__ void gl_lds16(const short* g, short* l) {
  __builtin_amdgcn_global_load_lds((const __attribute__((address_space(1))) void*)g,
                                   (__attribute__((address_space(3))) void*)l,
                                   16, 0, 0);
}

__global__ void cvt_kernel(const float* __restrict__ in, short* __restrict__ out, int n) {
  int i = (blockIdx.x * blockDim.x + threadIdx.x) * 4;
  if (i >= n) return;
  const float4 v = *reinterpret_cast<const float4*>(in + i);
  short4 o;
  o.x = f2bf(v.x); o.y = f2bf(v.y); o.z = f2bf(v.z); o.w = f2bf(v.w);
  *reinterpret_cast<short4*>(out + i) = o;
}

// C[M][N] = A[M][K] * B[N][K]^T (bf16 in, fp32 out), 128x128 tile, BK=32,
// m97 structure: global_load_lds width=16, 2 barriers per K-step.
__global__ __launch_bounds__(256) void gemm_lds(const short* __restrict__ A,
                                                const short* __restrict__ B,
                                                float* __restrict__ C,
                                                int M, int N, int K) {
  __shared__ short lA[128 * 32];
  __shared__ short lB[128 * 32];
  const int t = threadIdx.x;
  const int w = t >> 6, lane = t & 63;
  const int l15 = lane & 15, l4 = lane >> 4;
  const int tm = blockIdx.y * 128, tn = blockIdx.x * 128;
  const int wr = (w >> 1) * 64, wc = (w & 1) * 64;

  const int c0 = w * 128 + lane, c1 = c0 + 64;
  const short* gA0 = A + (size_t)(tm + (c0 >> 2)) * K + (c0 & 3) * 8;
  const short* gA1 = A + (size_t)(tm + (c1 >> 2)) * K + (c1 & 3) * 8;
  const short* gB0 = B + (size_t)(tn + (c0 >> 2)) * K + (c0 & 3) * 8;
  const short* gB1 = B + (size_t)(tn + (c1 >> 2)) * K + (c1 & 3) * 8;
  short* lA0 = lA + c0 * 8; short* lA1 = lA + c1 * 8;
  short* lB0 = lB + c0 * 8; short* lB1 = lB + c1 * 8;

  f32x4 acc[4][4] = {};

  for (int k0 = 0; k0 < K; k0 += 32) {
    gl_lds16(gA0 + k0, lA0);
    gl_lds16(gA1 + k0, lA1);
    gl_lds16(gB0 + k0, lB0);
    gl_lds16(gB1 + k0, lB1);
    __syncthreads();
    bf16x8 af[4], bfr[4];
#pragma unroll
    for (int m = 0; m < 4; ++m)
      af[m] = *reinterpret_cast<const bf16x8*>(lA + (wr + m * 16 + l15) * 32 + l4 * 8);
#pragma unroll
    for (int n = 0; n < 4; ++n)
      bfr[n] = *reinterpret_cast<const bf16x8*>(lB + (wc + n * 16 + l15) * 32 + l4 * 8);
#pragma unroll
    for (int m = 0; m < 4; ++m)
#pragma unroll
      for (int n = 0; n < 4; ++n)
        acc[m][n] = __builtin_amdgcn_mfma_f32_16x16x32_bf16(af[m], bfr[n], acc[m][n], 0, 0, 0);
    __syncthreads();
  }
#pragma unroll
  for (int m = 0; m < 4; ++m)
#pragma unroll
    for (int n = 0; n < 4; ++n)
#pragma unroll
      for (int r = 0; r < 4; ++r) {
        int rr = tm + wr + m * 16 + l4 * 4 + r;
        int cc = tn + wc + n * 16 + l15;
        C[(size_t)rr * N + cc] = acc[m][n][r];
      }
}

// qkv fp32 [S][6144] -> roped bf16 Q[NH][S][HD], K[NKV][S][HD], V[NKV][S][HD]
__global__ void rope_kernel(const float* __restrict__ qkv,
                            const float* __restrict__ cb,
                            const float* __restrict__ sb,
                            short* __restrict__ Q,
                            short* __restrict__ Kx,
                            short* __restrict__ V) {
  int tid = blockIdx.x * blockDim.x + threadIdx.x;
  int s = tid / QKVD;
  int j = tid - s * QKVD;
  int g = j / 768;
  int idx = j - g * 768;
  float val = qkv[tid];
  if (idx < 640) {
    int part = idx >> 7;  // 0..3 = q heads in group, 4 = k
    int d = idx & 127;
    int d2 = (d < 64) ? d + 64 : d - 64;
    float pv = qkv[(size_t)s * QKVD + g * 768 + part * 128 + d2];
    float c = cb[s * HD + d], sn = sb[s * HD + d];
    float ov = (d < 64) ? (val * c - pv * sn) : (val * c + pv * sn);
    if (part < 4) {
      int hh = g * 4 + part;
      Q[((size_t)hh * S_LEN + s) * HD + d] = f2bf(ov);
    } else {
      Kx[((size_t)g * S_LEN + s) * HD + d] = f2bf(ov);
    }
  } else {
    int d = idx - 640;
    V[((size_t)g * S_LEN + s) * HD + d] = f2bf(val);
  }
}

// V [NKVH][S][HD] -> Vt [NKVH][HD][S], 64x64 LDS tiles, coalesced both sides
__global__ __launch_bounds__(256) void vtrans_kernel(const short* __restrict__ V,
                                                     short* __restrict__ Vt) {
  __shared__ short tile[64][72];
  const int kvh = blockIdx.z;
  const int s0 = blockIdx.x * 64, d0 = blockIdx.y * 64;
  const int t = threadIdx.x;
  const short* Vb = V + (size_t)kvh * S_LEN * HD;
  short* Vtb = Vt + (size_t)kvh * HD * S_LEN;
#pragma unroll
  for (int i = 0; i < 2; ++i) {
    int sl = i * 32 + (t >> 3), dl = (t & 7) * 8;
    bf16x8 v = *reinterpret_cast<const bf16x8*>(Vb + (size_t)(s0 + sl) * HD + d0 + dl);
    *reinterpret_cast<bf16x8*>(&tile[sl][dl]) = v;
  }
  __syncthreads();
#pragma unroll
  for (int i = 0; i < 2; ++i) {
    int dl = i * 32 + (t >> 3), sl = (t & 7) * 8;
    bf16x8 o;
#pragma unroll
    for (int j = 0; j < 8; ++j) o[j] = tile[sl + j][dl];
    *reinterpret_cast<bf16x8*>(Vtb + (size_t)(d0 + dl) * S_LEN + s0 + sl) = o;
  }
}

// flash attention v3: block = (kvh, qt-pair-balanced); 4 waves = 4 heads of the
// KV group; each wave owns 32 q rows (2x16 frags). K tile (64x128) staged in
// LDS via global_load_lds, double-buffered, prefetched, source-XOR-swizzled.
// V^T read direct from global (L2-resident).
__global__ __launch_bounds__(256) void attn_kernel(const short* __restrict__ Q,
                                                   const short* __restrict__ Kx,
                                                   const short* __restrict__ Vt,
                                                   short* __restrict__ AO) {
  __shared__ short lK[2 * 64 * 128];   // 32 KiB, XOR-swizzled layout
  __shared__ short lP[4 * 32 * 72];    // per-wave P[32][64], stride 72
  const int tt = threadIdx.x;
  const int w = tt >> 6, lane = tt & 63;
  const int l15 = lane & 15, l4 = lane >> 4;
  const int kvh = blockIdx.x;
  const int yy = blockIdx.y;
  const int qt = (yy & 1) ? (63 - (yy >> 1)) : (yy >> 1);  // causal balance
  const int h = kvh * 4 + w;
  short* P = lP + w * (32 * 72);

  bf16x8 qf[2][4];
#pragma unroll
  for (int qa = 0; qa < 2; ++qa) {
    const short* qrow = Q + ((size_t)h * S_LEN + qt * 32 + qa * 16 + l15) * HD + l4 * 8;
#pragma unroll
    for (int fd = 0; fd < 4; ++fd)
      qf[qa][fd] = *reinterpret_cast<const bf16x8*>(qrow + fd * 32);
  }

  f32x4 o[2][8] = {};
  float m_run[2][4], lsum[2][4];
#pragma unroll
  for (int qa = 0; qa < 2; ++qa)
#pragma unroll
    for (int r = 0; r < 4; ++r) { m_run[qa][r] = -1e30f; lsum[qa][r] = 0.f; }

  const short* Kb = Kx + (size_t)kvh * S_LEN * HD;
  const short* Vb = Vt + (size_t)kvh * HD * S_LEN;  // [HD][S]
  const int nkt = (qt + 2) >> 1;

  // prologue: stage K tile 0 (source pre-swizzled so LDS-linear == swizzled)
#pragma unroll
  for (int i = 0; i < 4; ++i) {
    int c = tt + i * 256, row = c >> 4, jj = (c & 15) ^ (row & 7);
    gl_lds16(Kb + (size_t)row * HD + jj * 8, lK + c * 8);
  }
  __syncthreads();

  int cur = 0;
  for (int kt = 0; kt < nkt; ++kt) {
    const int c0 = kt * 64;
    if (kt + 1 < nkt) {  // prefetch next K tile into other buffer
      const short* Kg = Kb + (size_t)(c0 + 64) * HD;
      short* dst = lK + (cur ^ 1) * (64 * 128);
#pragma unroll
      for (int i = 0; i < 4; ++i) {
        int c = tt + i * 256, row = c >> 4, jj = (c & 15) ^ (row & 7);
        gl_lds16(Kg + (size_t)row * HD + jj * 8, dst + c * 8);
      }
    }
    // QK^T: S[32q][64kv]; K fragments from swizzled LDS, shared across qa
    const short* src = lK + cur * (64 * 128);
    f32x4 sf[2][4] = {};
#pragma unroll
    for (int n = 0; n < 4; ++n) {
      bf16x8 kf[4];
#pragma unroll
      for (int fd = 0; fd < 4; ++fd) {
        int row = n * 16 + l15, jp = (l4 + fd * 4) ^ (l15 & 7);
        kf[fd] = *reinterpret_cast<const bf16x8*>(src + row * 128 + jp * 8);
      }
#pragma unroll
      for (int fd = 0; fd < 4; ++fd)
        sf[0][n] = __builtin_amdgcn_mfma_f32_16x16x32_bf16(qf[0][fd], kf[fd], sf[0][n], 0, 0, 0);
#pragma unroll
      for (int fd = 0; fd < 4; ++fd)
        sf[1][n] = __builtin_amdgcn_mfma_f32_16x16x32_bf16(qf[1][fd], kf[fd], sf[1][n], 0, 0, 0);
    }
    const bool lastt = (kt == nkt - 1);
    float alpha[2][4];
#pragma unroll
    for (int qa = 0; qa < 2; ++qa) {
#pragma unroll
      for (int n = 0; n < 4; ++n)
#pragma unroll
        for (int r = 0; r < 4; ++r) {
          float v = sf[qa][n][r] * ATT_SCALE;
          if (lastt && (c0 + n * 16 + l15) > (qt * 32 + qa * 16 + l4 * 4 + r)) v = -1e30f;
          sf[qa][n][r] = v;
        }
#pragma unroll
      for (int r = 0; r < 4; ++r) {
        float mx = fmaxf(fmaxf(sf[qa][0][r], sf[qa][1][r]), fmaxf(sf[qa][2][r], sf[qa][3][r]));
        mx = fmaxf(mx, __shfl_xor(mx, 1, 64));
        mx = fmaxf(mx, __shfl_xor(mx, 2, 64));
        mx = fmaxf(mx, __shfl_xor(mx, 4, 64));
        mx = fmaxf(mx, __shfl_xor(mx, 8, 64));
        float mnew = fmaxf(m_run[qa][r], mx);
        alpha[qa][r] = __expf(m_run[qa][r] - mnew);
        m_run[qa][r] = mnew;
        float ps = 0.f;
#pragma unroll
        for (int n = 0; n < 4; ++n) {
          float e = __expf(sf[qa][n][r] - mnew);
          sf[qa][n][r] = e;
          ps += e;
        }
        lsum[qa][r] = lsum[qa][r] * alpha[qa][r] + ps;
      }
#pragma unroll
      for (int fd = 0; fd < 8; ++fd) {
        o[qa][fd][0] *= alpha[qa][0]; o[qa][fd][1] *= alpha[qa][1];
        o[qa][fd][2] *= alpha[qa][2]; o[qa][fd][3] *= alpha[qa][3];
      }
      // P -> LDS (A-fragment transpose), per-wave buffer
#pragma unroll
      for (int n = 0; n < 4; ++n)
#pragma unroll
        for (int r = 0; r < 4; ++r)
          P[(qa * 16 + l4 * 4 + r) * 72 + n * 16 + l15] = f2bf(sf[qa][n][r]);
    }
    asm volatile("s_waitcnt lgkmcnt(0)" ::: "memory");
    bf16x8 pf[2][2];
#pragma unroll
    for (int qa = 0; qa < 2; ++qa) {
      pf[qa][0] = *reinterpret_cast<const bf16x8*>(P + (qa * 16 + l15) * 72 + l4 * 8);
      pf[qa][1] = *reinterpret_cast<const bf16x8*>(P + (qa * 16 + l15) * 72 + 32 + l4 * 8);
    }
    // PV: O[32q][128d] += P[32q][64kv] * V[64kv][128d] (V^T direct, shared over qa)
#pragma unroll
    for (int fd = 0; fd < 8; ++fd) {
      const short* vrow = Vb + (size_t)(fd * 16 + l15) * S_LEN + c0 + l4 * 8;
      bf16x8 vf0 = *reinterpret_cast<const bf16x8*>(vrow);
      bf16x8 vf1 = *reinterpret_cast<const bf16x8*>(vrow + 32);
      o[0][fd] = __builtin_amdgcn_mfma_f32_16x16x32_bf16(pf[0][0], vf0, o[0][fd], 0, 0, 0);
      o[0][fd] = __builtin_amdgcn_mfma_f32_16x16x32_bf16(pf[0][1], vf1, o[0][fd], 0, 0, 0);
      o[1][fd] = __builtin_amdgcn_mfma_f32_16x16x32_bf16(pf[1][0], vf0, o[1][fd], 0, 0, 0);
      o[1][fd] = __builtin_amdgcn_mfma_f32_16x16x32_bf16(pf[1][1], vf1, o[1][fd], 0, 0, 0);
    }
    __syncthreads();  // drains vmcnt(0): next K tile landed; P/LDS reuse safe
    cur ^= 1;
  }
#pragma unroll
  for (int qa = 0; qa < 2; ++qa) {
    float inv[4];
#pragma unroll
    for (int r = 0; r < 4; ++r) {
      float s = lsum[qa][r];
      s += __shfl_xor(s, 1, 64);
      s += __shfl_xor(s, 2, 64);
      s += __shfl_xor(s, 4, 64);
      s += __shfl_xor(s, 8, 64);
      inv[r] = 1.f / s;
    }
#pragma unroll
    for (int fd = 0; fd < 8; ++fd)
#pragma unroll
      for (int r = 0; r < 4; ++r)
        AO[(size_t)(qt * 32 + qa * 16 + l4 * 4 + r) * HDIM + h * HD + fd * 16 + l15] =
            f2bf(o[qa][fd][r] * inv[r]);
  }
}

extern "C" void kernel_launch(void* const* d_in, const int* in_sizes, int n_in,
                              void* d_out, int out_size, void* d_ws, size_t ws_size,
                              hipStream_t stream) {
  const float* hidden = (const float*)d_in[0];
  const float* w_attn = (const float*)d_in[1];
  const float* w_proj = (const float*)d_in[2];
  const float* rcos = (const float*)d_in[3];
  const float* rsin = (const float*)d_in[4];
  float* out = (float*)d_out;
  char* ws = (char*)d_ws;

  // workspace layout (112 MiB total, overlaid):
  //  [0,16Mi)    Xb (bf16 X)          -> reused as AO after gemm1
  //  [16,64Mi)   Wab (bf16 w_attn)    -> after gemm1: Qb[16,32) Kb[32,36) Vb[36,40) Vtb[40,44)
  //  [64,112Mi)  QKVf (fp32 qkv)      -> reused as Wpb (bf16 w_proj) after rope
  short* Xb  = (short*)(ws);
  short* Wab = (short*)(ws + (16u << 20));
  short* Qb  = (short*)(ws + (16u << 20));
  short* Kb  = (short*)(ws + (32u << 20));
  short* Vb  = (short*)(ws + (36u << 20));
  short* Vtb = (short*)(ws + (40u << 20));
  float* QKVf = (float*)(ws + (64u << 20));
  short* Wpb = (short*)(ws + (64u << 20));
  short* AO  = Xb;

  const int nX = S_LEN * HDIM;
  const int nWa = QKVD * HDIM;
  const int nWp = HDIM * HDIM;

  cvt_kernel<<<nX / 1024, 256, 0, stream>>>(hidden, Xb, nX);
  cvt_kernel<<<nWa / 1024, 256, 0, stream>>>(w_attn, Wab, nWa);
  gemm_lds<<<dim3(QKVD / 128, S_LEN / 128), 256, 0, stream>>>(Xb, Wab, QKVf, S_LEN, QKVD, HDIM);
  rope_kernel<<<(S_LEN * QKVD) / 256, 256, 0, stream>>>(QKVf, rcos, rsin, Qb, Kb, Vb);
  vtrans_kernel<<<dim3(S_LEN / 64, HD / 64, NKVH), 256, 0, stream>>>(Vb, Vtb);
  cvt_kernel<<<nWp / 1024, 256, 0, stream>>>(w_proj, Wpb, nWp);
  attn_kernel<<<dim3(NKVH, 64), 256, 0, stream>>>(Qb, Kb, Vtb, AO);
  gemm_lds<<<dim3(HDIM / 128, S_LEN / 128), 256, 0, stream>>>(AO, Wpb, out, S_LEN, HDIM, HDIM);
}